// Round 1
// 2169.836 us; speedup vs baseline: 1.1339x; 1.1339x over previous
//
#include <hip/hip_runtime.h>
#include <math.h>

#define NN 16384
#define DD 1024
#define HH 4096
#define EE 8
#define OUTD 4096

typedef unsigned short u16;
typedef short v8s __attribute__((ext_vector_type(8)));
typedef float v4f __attribute__((ext_vector_type(4)));

__device__ __forceinline__ u16 f2bf(float f) {
    unsigned int u = __float_as_uint(f);
    u = (u + 0x7fffu + ((u >> 16) & 1u)) >> 16;
    return (u16)u;
}

// async global->LDS, 16B per lane; LDS dest = wave-uniform base + lane*16
__device__ __forceinline__ void cp16(const u16* g, u16* l) {
    __builtin_amdgcn_global_load_lds(
        (const __attribute__((address_space(1))) unsigned int*)g,
        (__attribute__((address_space(3))) unsigned int*)l, 16, 0, 0);
}

// ---------------------------------------------------------------------------
// elementwise f32 -> bf16 (float4 vectorized)
__global__ __launch_bounds__(256) void cvt_bf16(const float* __restrict__ in,
                                                u16* __restrict__ out, int n4) {
    int i = blockIdx.x * 256 + threadIdx.x;
    if (i < n4) {
        float4 v = ((const float4*)in)[i];
        ushort4 o;
        o.x = f2bf(v.x); o.y = f2bf(v.y); o.z = f2bf(v.z); o.w = f2bf(v.w);
        ((ushort4*)out)[i] = o;
    }
}

// ---------------------------------------------------------------------------
// transpose + cast: in [rows][cols] f32  ->  out [cols][rows] bf16, per blockIdx.z matrix
__global__ __launch_bounds__(256) void transpose_cast(const float* __restrict__ in,
                                                      u16* __restrict__ out,
                                                      int rows, int cols) {
    __shared__ float t[32][33];
    const float* inp = in + (size_t)blockIdx.z * rows * cols;
    u16* outp = out + (size_t)blockIdx.z * rows * cols;
    int c0 = blockIdx.x * 32, r0 = blockIdx.y * 32;
    int tx = threadIdx.x & 31, ty = threadIdx.x >> 5;   // 32 x 8
#pragma unroll
    for (int i = 0; i < 4; ++i)
        t[ty + i * 8][tx] = inp[(size_t)(r0 + ty + i * 8) * cols + c0 + tx];
    __syncthreads();
#pragma unroll
    for (int i = 0; i < 4; ++i)
        outp[(size_t)(c0 + ty + i * 8) * rows + r0 + tx] = f2bf(t[tx][ty + i * 8]);
}

// ---------------------------------------------------------------------------
// Gt[e][d] = sum_j W_in[d][j] * Wg[j][e]   (fp32, exact gate path)
// cvec[e]  = sum_j b_in[j]   * Wg[j][e]
__global__ __launch_bounds__(256) void compute_G(const float* __restrict__ Win,
                                                 const float* __restrict__ Wg,
                                                 const float* __restrict__ b_in,
                                                 float* __restrict__ Gt,
                                                 float* __restrict__ cvec) {
    int tid = blockIdx.x * 256 + threadIdx.x;
    if (tid < EE * DD) {
        int e = tid >> 10, d = tid & 1023;
        float s = 0.f;
        for (int j = 0; j < DD; ++j) s += Win[(size_t)d * DD + j] * Wg[j * EE + e];
        Gt[e * DD + d] = s;
    } else if (tid < EE * DD + EE) {
        int e = tid - EE * DD;
        float s = 0.f;
        for (int j = 0; j < DD; ++j) s += b_in[j] * Wg[j * EE + e];
        cvec[e] = s;
    }
}

// ---------------------------------------------------------------------------
// gate: fp32 logits = x@Gt + c, softmax top-2 renorm, build per-expert lists
__global__ __launch_bounds__(256) void gate_kernel(const float* __restrict__ x,
                                                   const float* __restrict__ Gt,
                                                   const float* __restrict__ cvec,
                                                   int* __restrict__ counts,
                                                   int* __restrict__ toklist,
                                                   float* __restrict__ wtlist) {
    int wave = threadIdx.x >> 6, lane = threadIdx.x & 63;
    int t = blockIdx.x * 4 + wave;
    const float* xr = x + (size_t)t * DD;
    float p[EE];
#pragma unroll
    for (int e = 0; e < EE; ++e) p[e] = 0.f;
    for (int it = 0; it < DD / 64; ++it) {
        int d = it * 64 + lane;
        float xv = xr[d];
#pragma unroll
        for (int e = 0; e < EE; ++e) p[e] += xv * Gt[e * DD + d];
    }
#pragma unroll
    for (int e = 0; e < EE; ++e) {
        float v = p[e];
#pragma unroll
        for (int m = 32; m >= 1; m >>= 1) v += __shfl_xor(v, m);
        p[e] = v;
    }
    if (lane == 0) {
        float l[EE];
#pragma unroll
        for (int e = 0; e < EE; ++e) l[e] = p[e] + cvec[e];
        int i0 = 0; float v0 = l[0];
#pragma unroll
        for (int e = 1; e < EE; ++e) if (l[e] > v0) { v0 = l[e]; i0 = e; }
        int i1 = -1; float v1 = -1e30f;
#pragma unroll
        for (int e = 0; e < EE; ++e) if (e != i0 && l[e] > v1) { v1 = l[e]; i1 = e; }
        float e1 = __expf(v1 - v0);            // e0 = 1
        float inv = 1.f / (1.f + e1);
        float w0 = inv, w1 = e1 * inv;
        int pos0 = atomicAdd(&counts[i0], 1);
        toklist[i0 * NN + pos0] = t; wtlist[i0 * NN + pos0] = w0;
        int pos1 = atomicAdd(&counts[i1], 1);
        toklist[i1 * NN + pos1] = t; wtlist[i1 * NN + pos1] = w1;
    }
}

__global__ void offsets_kernel(const int* __restrict__ counts, int* __restrict__ offs) {
    if (threadIdx.x == 0) {
        int a = 0;
        for (int e = 0; e < EE; ++e) { offs[e] = a; a += counts[e]; }
    }
}

// ---------------------------------------------------------------------------
// gemm_bt: C[M,128-tiles x N] = A[M,K] (k-contig) x Bt[N,K] (k-contig)
// 128x128 tile, BK=32, 4 waves, 4x4 mfma_f32_16x16x32_bf16 per wave.
// 3-deep LDS pipeline: counted vmcnt (never drained mid-loop), raw s_barrier
// with compiler memory fences, XOR chunk-swizzled LDS (both-sides involution,
// rule #21), XCD-chunked block swizzle (T1), setprio around MFMA cluster (T5).
// MODE 0: +bias        -> bf16 store        (h = x@W_in + b_in)
// MODE 1: gather A rows by token list, +bias, relu -> bf16 store at slot rows (he)
// MODE 2: A = he slot rows, +bias, *gate weight, atomicAdd scatter to moe_f32 (ye)
// MODE 3: plain -> fp32 store (head)
template <int MODE, int K, int LDC>
__global__ __launch_bounds__(256, 2) void gemm_bt(
    const u16* __restrict__ A, const u16* __restrict__ Btb,
    u16* __restrict__ outb, float* __restrict__ outf,
    const float* __restrict__ biasb,
    const int* __restrict__ toklist, const float* __restrict__ wtlist,
    const int* __restrict__ counts, const int* __restrict__ offsets,
    float* __restrict__ moe) {
    __shared__ __align__(16) u16 As[3][128 * 32];   // 3-deep pipeline buffers
    __shared__ __align__(16) u16 Bs[3][128 * 32];   // total LDS 48KB -> 3 blocks/CU

    // ---- XCD-chunked bijective block swizzle (all grids are %8 == 0) ----
    constexpr int GX = (MODE == 1 || MODE == 2) ? EE * 128 : NN / 128;
    constexpr int GY = LDC / 128;
    constexpr int NWG = GX * GY;
    constexpr int QC = NWG / 8;
    static_assert(NWG % 8 == 0, "xcd swizzle needs nwg%8==0");

    const int wg = blockIdx.x + GX * blockIdx.y;
    const int lid = (wg & 7) * QC + (wg >> 3);
    const int bx = lid & (GX - 1);     // GX is a power of two
    const int by = lid / GX;

    int e = 0, mt = bx, cnt = 0, ofs = 0;
    if (MODE == 1 || MODE == 2) {
        e = bx >> 7; mt = bx & 127;
        cnt = counts[e];
        if (mt * 128 >= cnt) return;
        ofs = offsets[e];
    }
    const int m0 = mt * 128;
    const int n0 = by * 128;

    const u16* Bt = Btb;
    const float* bias = biasb;
    if (MODE == 1) { Bt += (size_t)e * HH * DD; bias += e * HH; }
    if (MODE == 2) { Bt += (size_t)e * DD * HH; bias += e * DD; }

    const int lane = threadIdx.x & 63;
    const int wave = threadIdx.x >> 6;
    const int rl = lane >> 2;          // row within a 16-row staging slot
    const int kc = lane & 3;           // 16B chunk within 64B row
    // write-side XOR swizzle: LDS dest stays linear (global_load_lds rule),
    // global source chunk is permuted so data lands swizzled.
    const int kcs = kc ^ ((rl >> 1) & 3);

    const u16* aS[2];
    const u16* bS[2];
#pragma unroll
    for (int s = 0; s < 2; ++s) {
        int trow = wave * 32 + s * 16 + rl;   // tile row 0..127
        long arow;
        if (MODE == 1) {
            int rr = m0 + trow; if (rr >= cnt) rr = cnt - 1;
            arow = toklist[e * NN + rr];
        } else if (MODE == 2) {
            int rr = m0 + trow; if (rr >= cnt) rr = cnt - 1;
            arow = ofs + rr;
        } else {
            arow = m0 + trow;
        }
        aS[s] = A + (size_t)arow * K + kcs * 8;
        bS[s] = Bt + (size_t)(n0 + trow) * K + kcs * 8;
    }
    u16* aL[2] = { &As[0][(wave * 32) * 32], &As[0][(wave * 32 + 16) * 32] };
    u16* bL[2] = { &Bs[0][(wave * 32) * 32], &Bs[0][(wave * 32 + 16) * 32] };

    const int wm = wave & 1, wn = wave >> 1;
    const int fr = lane & 15;
    // read-side XOR swizzle: same involution of the 16B chunk index
    const int kswz = ((lane >> 4) ^ ((fr >> 1) & 3)) * 8;

    v4f acc[4][4];
#pragma unroll
    for (int i = 0; i < 4; ++i)
#pragma unroll
        for (int j = 0; j < 4; ++j)
#pragma unroll
            for (int c = 0; c < 4; ++c) acc[i][j][c] = 0.f;

    auto STAGE = [&](int kt, int buf) {
#pragma unroll
        for (int s = 0; s < 2; ++s) {
            cp16(aS[s] + kt * 32, aL[s] + buf * 4096);
            cp16(bS[s] + kt * 32, bL[s] + buf * 4096);
        }
    };

    constexpr int NIT = K / 32;
    // prologue: tiles 0 and 1 in flight (4 cp16 per thread per tile)
    STAGE(0, 0);
    STAGE(1, 1);

    int cur = 0, pre = 2;
    for (int it = 0; it < NIT; ++it) {
        if (it + 2 < NIT) {
            STAGE(it + 2, pre);
            // 12 outstanding; wait until oldest 4 (tile `it`) landed
            asm volatile("s_waitcnt vmcnt(8)" ::: "memory");
        } else if (it + 2 == NIT) {
            asm volatile("s_waitcnt vmcnt(4)" ::: "memory");
        } else {
            asm volatile("s_waitcnt vmcnt(0)" ::: "memory");
        }
        __builtin_amdgcn_s_barrier();          // all waves' tile-`it` staging done
        asm volatile("" ::: "memory");         // keep ds_reads below the barrier

        v8s af[4], bv[4];
#pragma unroll
        for (int i = 0; i < 4; ++i)
            af[i] = *(const v8s*)&As[cur][(wm * 64 + i * 16 + fr) * 32 + kswz];
#pragma unroll
        for (int j = 0; j < 4; ++j)
            bv[j] = *(const v8s*)&Bs[cur][(wn * 64 + j * 16 + fr) * 32 + kswz];

        __builtin_amdgcn_s_setprio(1);
#pragma unroll
        for (int i = 0; i < 4; ++i)
#pragma unroll
            for (int j = 0; j < 4; ++j)
                acc[i][j] = __builtin_amdgcn_mfma_f32_16x16x32_bf16(af[i], bv[j], acc[i][j], 0, 0, 0);
        __builtin_amdgcn_s_setprio(0);

        asm volatile("" ::: "memory");         // keep ds_reads above the barrier
        __builtin_amdgcn_s_barrier();          // all reads of buf[cur] consumed
        cur = cur == 2 ? 0 : cur + 1;
        pre = pre == 2 ? 0 : pre + 1;
    }

    const int quad = (lane >> 4) * 4;
#pragma unroll
    for (int i = 0; i < 4; ++i) {
#pragma unroll
        for (int r = 0; r < 4; ++r) {
            int rloc = wm * 64 + i * 16 + quad + r;
            int grow = m0 + rloc;
            if ((MODE == 1 || MODE == 2) && grow >= cnt) continue;
            int tok = 0; float wgt = 0.f;
            if (MODE == 2) { tok = toklist[e * NN + grow]; wgt = wtlist[e * NN + grow]; }
#pragma unroll
            for (int j = 0; j < 4; ++j) {
                int col = n0 + wn * 64 + j * 16 + fr;
                float v = acc[i][j][r];
                if (MODE == 0) {
                    outb[(size_t)grow * LDC + col] = f2bf(v + bias[col]);
                } else if (MODE == 1) {
                    float t = v + bias[col];
                    t = t > 0.f ? t : 0.f;
                    outb[(size_t)(ofs + grow) * LDC + col] = f2bf(t);
                } else if (MODE == 2) {
                    atomicAdd(&moe[(size_t)tok * LDC + col], wgt * (v + bias[col]));
                } else {
                    outf[(size_t)grow * LDC + col] = v;
                }
            }
        }
    }
}

// ---------------------------------------------------------------------------
extern "C" void kernel_launch(void* const* d_in, const int* in_sizes, int n_in,
                              void* d_out, int out_size, void* d_ws, size_t ws_size,
                              hipStream_t stream) {
    const float* x    = (const float*)d_in[0];
    const float* Win  = (const float*)d_in[1];
    const float* b_in = (const float*)d_in[2];
    const float* Wg   = (const float*)d_in[3];
    const float* W1   = (const float*)d_in[4];
    const float* b1   = (const float*)d_in[5];
    const float* W2   = (const float*)d_in[6];
    const float* b2   = (const float*)d_in[7];
    const float* Wh   = (const float*)d_in[8];
    float* out = (float*)d_out;

    // workspace layout (256B aligned)
    char* p = (char*)d_ws;
    size_t off = 0;
    auto alloc = [&](size_t bytes) {
        char* r = p + off;
        off = (off + bytes + 255) & ~(size_t)255;
        return r;
    };
    u16*   x_bf   = (u16*)alloc((size_t)NN * DD * 2);
    u16*   wint   = (u16*)alloc((size_t)DD * DD * 2);
    u16*   w1t    = (u16*)alloc((size_t)EE * DD * HH * 2);
    u16*   w2t    = (u16*)alloc((size_t)EE * DD * HH * 2);
    u16*   wht    = (u16*)alloc((size_t)DD * OUTD * 2);
    u16*   h_bf   = (u16*)alloc((size_t)NN * DD * 2);
    float* moe_f  = (float*)alloc((size_t)NN * DD * 4);
    u16*   moe_bf = (u16*)alloc((size_t)NN * DD * 2);
    float* Gt     = (float*)alloc((size_t)EE * DD * 4);
    float* cvec   = (float*)alloc(256);
    int*   counts = (int*)alloc(256);
    int*   offs   = (int*)alloc(256);
    int*   tok    = (int*)alloc((size_t)EE * NN * 4);
    float* wt     = (float*)alloc((size_t)EE * NN * 4);
    if (off > ws_size) return;  // workspace too small — fail loudly via wrong output

    u16* he = (u16*)d_out;  // 2N x H bf16 == exactly out_size*4 bytes; head GEMM overwrites

    hipMemsetAsync(counts, 0, 256, stream);
    hipMemsetAsync(moe_f, 0, (size_t)NN * DD * 4, stream);

    // conversions / transposes
    cvt_bf16<<<dim3(NN * DD / 4 / 256), 256, 0, stream>>>(x, x_bf, NN * DD / 4);
    transpose_cast<<<dim3(DD / 32, DD / 32, 1), 256, 0, stream>>>(Win, wint, DD, DD);
    transpose_cast<<<dim3(HH / 32, DD / 32, EE), 256, 0, stream>>>(W1, w1t, DD, HH);
    transpose_cast<<<dim3(DD / 32, HH / 32, EE), 256, 0, stream>>>(W2, w2t, HH, DD);
    transpose_cast<<<dim3(OUTD / 32, DD / 32, 1), 256, 0, stream>>>(Wh, wht, DD, OUTD);
    compute_G<<<dim3((EE * DD + EE + 255) / 256), 256, 0, stream>>>(Win, Wg, b_in, Gt, cvec);

    // h = x@W_in + b_in  (bf16 out)
    gemm_bt<0, DD, DD><<<dim3(NN / 128, DD / 128), 256, 0, stream>>>(
        x_bf, wint, h_bf, nullptr, b_in, nullptr, nullptr, nullptr, nullptr, nullptr);

    // routing (exact fp32 logits)
    gate_kernel<<<dim3(NN / 4), 256, 0, stream>>>(x, Gt, cvec, counts, tok, wt);
    offsets_kernel<<<dim3(1), 64, 0, stream>>>(counts, offs);

    // he = relu(h_gathered @ W1[e] + b1[e])  -> bf16 slots in d_out
    gemm_bt<1, DD, HH><<<dim3(EE * 128, HH / 128), 256, 0, stream>>>(
        h_bf, w1t, he, nullptr, b1, tok, wt, counts, offs, nullptr);

    // moe += w * (he @ W2[e] + b2[e])  (atomic fp32 scatter)
    gemm_bt<2, HH, DD><<<dim3(EE * 128, DD / 128), 256, 0, stream>>>(
        he, w2t, nullptr, nullptr, b2, tok, wt, counts, offs, moe_f);

    cvt_bf16<<<dim3(NN * DD / 4 / 256), 256, 0, stream>>>(moe_f, moe_bf, NN * DD / 4);

    // out = moe @ W_head  (fp32 store)
    gemm_bt<3, DD, OUTD><<<dim3(NN / 128, OUTD / 128), 256, 0, stream>>>(
        moe_bf, wht, nullptr, out, nullptr, nullptr, nullptr, nullptr, nullptr, nullptr);
}

// Round 2
// 2006.330 us; speedup vs baseline: 1.2263x; 1.0815x over previous
//
#include <hip/hip_runtime.h>
#include <math.h>

#define NN 16384
#define DD 1024
#define HH 4096
#define EE 8
#define OUTD 4096

typedef unsigned short u16;
typedef short v8s __attribute__((ext_vector_type(8)));
typedef float v4f __attribute__((ext_vector_type(4)));

__device__ __forceinline__ u16 f2bf(float f) {
    unsigned int u = __float_as_uint(f);
    u = (u + 0x7fffu + ((u >> 16) & 1u)) >> 16;
    return (u16)u;
}

// async global->LDS, 16B per lane; LDS dest = wave-uniform base + lane*16
__device__ __forceinline__ void cp16(const u16* g, u16* l) {
    __builtin_amdgcn_global_load_lds(
        (const __attribute__((address_space(1))) unsigned int*)g,
        (__attribute__((address_space(3))) unsigned int*)l, 16, 0, 0);
}

// ---------------------------------------------------------------------------
// elementwise f32 -> bf16 (float4 vectorized)
__global__ __launch_bounds__(256) void cvt_bf16(const float* __restrict__ in,
                                                u16* __restrict__ out, int n4) {
    int i = blockIdx.x * 256 + threadIdx.x;
    if (i < n4) {
        float4 v = ((const float4*)in)[i];
        ushort4 o;
        o.x = f2bf(v.x); o.y = f2bf(v.y); o.z = f2bf(v.z); o.w = f2bf(v.w);
        ((ushort4*)out)[i] = o;
    }
}

// ---------------------------------------------------------------------------
// transpose + cast: in [rows][cols] f32  ->  out [cols][rows] bf16, per blockIdx.z matrix
__global__ __launch_bounds__(256) void transpose_cast(const float* __restrict__ in,
                                                      u16* __restrict__ out,
                                                      int rows, int cols) {
    __shared__ float t[32][33];
    const float* inp = in + (size_t)blockIdx.z * rows * cols;
    u16* outp = out + (size_t)blockIdx.z * rows * cols;
    int c0 = blockIdx.x * 32, r0 = blockIdx.y * 32;
    int tx = threadIdx.x & 31, ty = threadIdx.x >> 5;   // 32 x 8
#pragma unroll
    for (int i = 0; i < 4; ++i)
        t[ty + i * 8][tx] = inp[(size_t)(r0 + ty + i * 8) * cols + c0 + tx];
    __syncthreads();
#pragma unroll
    for (int i = 0; i < 4; ++i)
        outp[(size_t)(c0 + ty + i * 8) * rows + r0 + tx] = f2bf(t[tx][ty + i * 8]);
}

// ---------------------------------------------------------------------------
// Gt[e][d] = sum_j W_in[d][j] * Wg[j][e]   (fp32, exact gate path)
// cvec[e]  = sum_j b_in[j]   * Wg[j][e]
// One wave per output dot product: Win reads coalesced (lane = j mod 64),
// shuffle-tree reduce. Replaces serial per-thread 1024-iter loops that were
// latency-bound on uncoalesced 4B loads.
__global__ __launch_bounds__(256) void compute_G(const float* __restrict__ Win,
                                                 const float* __restrict__ Wg,
                                                 const float* __restrict__ b_in,
                                                 float* __restrict__ Gt,
                                                 float* __restrict__ cvec) {
    int wid = (blockIdx.x * 256 + threadIdx.x) >> 6;
    int lane = threadIdx.x & 63;
    if (wid < EE * DD) {
        int e = wid >> 10, d = wid & 1023;
        float s = 0.f;
#pragma unroll
        for (int i = 0; i < DD / 64; ++i) {
            int j = i * 64 + lane;
            s += Win[(size_t)d * DD + j] * Wg[j * EE + e];
        }
#pragma unroll
        for (int m = 32; m >= 1; m >>= 1) s += __shfl_xor(s, m);
        if (lane == 0) Gt[e * DD + d] = s;
    } else if (wid < EE * DD + EE) {
        int e = wid - EE * DD;
        float s = 0.f;
#pragma unroll
        for (int i = 0; i < DD / 64; ++i) {
            int j = i * 64 + lane;
            s += b_in[j] * Wg[j * EE + e];
        }
#pragma unroll
        for (int m = 32; m >= 1; m >>= 1) s += __shfl_xor(s, m);
        if (lane == 0) cvec[e] = s;
    }
}

// ---------------------------------------------------------------------------
// gate: fp32 logits = x@Gt + c, softmax top-2 renorm, build per-expert lists
__global__ __launch_bounds__(256) void gate_kernel(const float* __restrict__ x,
                                                   const float* __restrict__ Gt,
                                                   const float* __restrict__ cvec,
                                                   int* __restrict__ counts,
                                                   int* __restrict__ toklist,
                                                   float* __restrict__ wtlist) {
    int wave = threadIdx.x >> 6, lane = threadIdx.x & 63;
    int t = blockIdx.x * 4 + wave;
    const float* xr = x + (size_t)t * DD;
    float p[EE];
#pragma unroll
    for (int e = 0; e < EE; ++e) p[e] = 0.f;
    for (int it = 0; it < DD / 64; ++it) {
        int d = it * 64 + lane;
        float xv = xr[d];
#pragma unroll
        for (int e = 0; e < EE; ++e) p[e] += xv * Gt[e * DD + d];
    }
#pragma unroll
    for (int e = 0; e < EE; ++e) {
        float v = p[e];
#pragma unroll
        for (int m = 32; m >= 1; m >>= 1) v += __shfl_xor(v, m);
        p[e] = v;
    }
    if (lane == 0) {
        float l[EE];
#pragma unroll
        for (int e = 0; e < EE; ++e) l[e] = p[e] + cvec[e];
        int i0 = 0; float v0 = l[0];
#pragma unroll
        for (int e = 1; e < EE; ++e) if (l[e] > v0) { v0 = l[e]; i0 = e; }
        int i1 = -1; float v1 = -1e30f;
#pragma unroll
        for (int e = 0; e < EE; ++e) if (e != i0 && l[e] > v1) { v1 = l[e]; i1 = e; }
        float e1 = __expf(v1 - v0);            // e0 = 1
        float inv = 1.f / (1.f + e1);
        float w0 = inv, w1 = e1 * inv;
        int pos0 = atomicAdd(&counts[i0], 1);
        toklist[i0 * NN + pos0] = t; wtlist[i0 * NN + pos0] = w0;
        int pos1 = atomicAdd(&counts[i1], 1);
        toklist[i1 * NN + pos1] = t; wtlist[i1 * NN + pos1] = w1;
    }
}

__global__ void offsets_kernel(const int* __restrict__ counts, int* __restrict__ offs) {
    if (threadIdx.x == 0) {
        int a = 0;
        for (int e = 0; e < EE; ++e) { offs[e] = a; a += counts[e]; }
    }
}

// ---------------------------------------------------------------------------
// gemm_bt: C[M,128-tiles x N] = A[M,K] (k-contig) x Bt[N,K] (k-contig)
// 128x128 tile, BK=32, 4 waves, 4x4 mfma_f32_16x16x32_bf16 per wave.
// 3-deep LDS pipeline, counted vmcnt, XOR chunk-swizzled LDS (0 bank conflicts),
// setprio around MFMA cluster.
// XCD-aware ordering (mode-specific, both bijective):
//   modes 1/3 (A small, N wide): by-STRIPE — XCD c owns by in [c*SH,(c+1)*SH),
//     bx-outer / by-inner: B-slice (~1MB) L2-resident, A-tile reused by SH
//     consecutive co-XCD blocks.
//   modes 0/2 (A large, N narrow): bx-CHUNK — XCD c owns bx in [c*CW,(c+1)*CW),
//     by-inner: each A-tile's GY blocks run consecutively on one XCD ->
//     A fetched ~once globally (mode 2: was ~8x = ~2GB of L2-miss traffic).
// MODE 0: +bias        -> bf16 store        (h = x@W_in + b_in)
// MODE 1: gather A rows by token list, +bias, relu -> bf16 store at slot rows (he)
// MODE 2: A = he slot rows, +bias, *gate weight, atomicAdd scatter to moe_f32 (ye)
// MODE 3: plain -> fp32 store (head)
template <int MODE, int K, int LDC>
__global__ __launch_bounds__(256, 3) void gemm_bt(
    const u16* __restrict__ A, const u16* __restrict__ Btb,
    u16* __restrict__ outb, float* __restrict__ outf,
    const float* __restrict__ biasb,
    const int* __restrict__ toklist, const float* __restrict__ wtlist,
    const int* __restrict__ counts, const int* __restrict__ offsets,
    float* __restrict__ moe) {
    __shared__ __align__(16) u16 As[3][128 * 32];   // 3-deep pipeline buffers
    __shared__ __align__(16) u16 Bs[3][128 * 32];   // total LDS 48KB -> 3 blocks/CU

    constexpr int GX = (MODE == 1 || MODE == 2) ? EE * 128 : NN / 128;
    constexpr int GY = LDC / 128;
    static_assert(GX % 8 == 0 && GY % 8 == 0 || (MODE == 1 || MODE == 3),
                  "swizzle divisibility");

    const int wg = blockIdx.x + GX * blockIdx.y;
    const int c = wg & 7;          // XCD (round-robin dispatch assumption)
    const int q = wg >> 3;         // index within this XCD's chunk
    int bx, by;
    if (MODE == 0 || MODE == 2) {
        constexpr int CW = GX / 8;
        static_assert(GX % 8 == 0, "bx-chunk needs GX%8==0");
        bx = c * CW + q / GY;
        by = q % GY;
    } else {
        constexpr int SH = GY / 8;
        static_assert(GY % 8 == 0, "by-stripe needs GY%8==0");
        bx = q / SH;
        by = c * SH + q % SH;
    }

    int e = 0, mt = bx, cnt = 0, ofs = 0;
    if (MODE == 1 || MODE == 2) {
        e = bx >> 7; mt = bx & 127;
        cnt = counts[e];
        if (mt * 128 >= cnt) return;
        ofs = offsets[e];
    }
    const int m0 = mt * 128;
    const int n0 = by * 128;

    const u16* Bt = Btb;
    const float* bias = biasb;
    if (MODE == 1) { Bt += (size_t)e * HH * DD; bias += e * HH; }
    if (MODE == 2) { Bt += (size_t)e * DD * HH; bias += e * DD; }

    const int lane = threadIdx.x & 63;
    const int wave = threadIdx.x >> 6;
    const int rl = lane >> 2;          // row within a 16-row staging slot
    const int kc = lane & 3;           // 16B chunk within 64B row
    // write-side XOR swizzle: LDS dest stays linear (global_load_lds rule),
    // global source chunk is permuted so data lands swizzled.
    const int kcs = kc ^ ((rl >> 1) & 3);

    const u16* aS[2];
    const u16* bS[2];
#pragma unroll
    for (int s = 0; s < 2; ++s) {
        int trow = wave * 32 + s * 16 + rl;   // tile row 0..127
        long arow;
        if (MODE == 1) {
            int rr = m0 + trow; if (rr >= cnt) rr = cnt - 1;
            arow = toklist[e * NN + rr];
        } else if (MODE == 2) {
            int rr = m0 + trow; if (rr >= cnt) rr = cnt - 1;
            arow = ofs + rr;
        } else {
            arow = m0 + trow;
        }
        aS[s] = A + (size_t)arow * K + kcs * 8;
        bS[s] = Bt + (size_t)(n0 + trow) * K + kcs * 8;
    }
    u16* aL[2] = { &As[0][(wave * 32) * 32], &As[0][(wave * 32 + 16) * 32] };
    u16* bL[2] = { &Bs[0][(wave * 32) * 32], &Bs[0][(wave * 32 + 16) * 32] };

    const int wm = wave & 1, wn = wave >> 1;
    const int fr = lane & 15;
    // read-side XOR swizzle: same involution of the 16B chunk index
    const int kswz = ((lane >> 4) ^ ((fr >> 1) & 3)) * 8;

    v4f acc[4][4];
#pragma unroll
    for (int i = 0; i < 4; ++i)
#pragma unroll
        for (int j = 0; j < 4; ++j)
#pragma unroll
            for (int c2 = 0; c2 < 4; ++c2) acc[i][j][c2] = 0.f;

    auto STAGE = [&](int kt, int buf) {
#pragma unroll
        for (int s = 0; s < 2; ++s) {
            cp16(aS[s] + kt * 32, aL[s] + buf * 4096);
            cp16(bS[s] + kt * 32, bL[s] + buf * 4096);
        }
    };

    constexpr int NIT = K / 32;
    // prologue: tiles 0 and 1 in flight (4 cp16 per thread per tile)
    STAGE(0, 0);
    STAGE(1, 1);

    int cur = 0, pre = 2;
    for (int it = 0; it < NIT; ++it) {
        if (it + 2 < NIT) {
            STAGE(it + 2, pre);
            // 12 outstanding; wait until oldest 4 (tile `it`) landed
            asm volatile("s_waitcnt vmcnt(8)" ::: "memory");
        } else if (it + 2 == NIT) {
            asm volatile("s_waitcnt vmcnt(4)" ::: "memory");
        } else {
            asm volatile("s_waitcnt vmcnt(0)" ::: "memory");
        }
        __builtin_amdgcn_s_barrier();          // all waves' tile-`it` staging done
        asm volatile("" ::: "memory");         // keep ds_reads below the barrier

        v8s af[4], bv[4];
#pragma unroll
        for (int i = 0; i < 4; ++i)
            af[i] = *(const v8s*)&As[cur][(wm * 64 + i * 16 + fr) * 32 + kswz];
#pragma unroll
        for (int j = 0; j < 4; ++j)
            bv[j] = *(const v8s*)&Bs[cur][(wn * 64 + j * 16 + fr) * 32 + kswz];

        __builtin_amdgcn_s_setprio(1);
#pragma unroll
        for (int i = 0; i < 4; ++i)
#pragma unroll
            for (int j = 0; j < 4; ++j)
                acc[i][j] = __builtin_amdgcn_mfma_f32_16x16x32_bf16(af[i], bv[j], acc[i][j], 0, 0, 0);
        __builtin_amdgcn_s_setprio(0);

        asm volatile("" ::: "memory");         // keep ds_reads above the barrier
        __builtin_amdgcn_s_barrier();          // all reads of buf[cur] consumed
        cur = cur == 2 ? 0 : cur + 1;
        pre = pre == 2 ? 0 : pre + 1;
    }

    const int quad = (lane >> 4) * 4;
#pragma unroll
    for (int i = 0; i < 4; ++i) {
#pragma unroll
        for (int r = 0; r < 4; ++r) {
            int rloc = wm * 64 + i * 16 + quad + r;
            int grow = m0 + rloc;
            if ((MODE == 1 || MODE == 2) && grow >= cnt) continue;
            int tok = 0; float wgt = 0.f;
            if (MODE == 2) { tok = toklist[e * NN + grow]; wgt = wtlist[e * NN + grow]; }
#pragma unroll
            for (int j = 0; j < 4; ++j) {
                int col = n0 + wn * 64 + j * 16 + fr;
                float v = acc[i][j][r];
                if (MODE == 0) {
                    outb[(size_t)grow * LDC + col] = f2bf(v + bias[col]);
                } else if (MODE == 1) {
                    float t = v + bias[col];
                    t = t > 0.f ? t : 0.f;
                    outb[(size_t)(ofs + grow) * LDC + col] = f2bf(t);
                } else if (MODE == 2) {
                    atomicAdd(&moe[(size_t)tok * LDC + col], wgt * (v + bias[col]));
                } else {
                    outf[(size_t)grow * LDC + col] = v;
                }
            }
        }
    }
}

// ---------------------------------------------------------------------------
extern "C" void kernel_launch(void* const* d_in, const int* in_sizes, int n_in,
                              void* d_out, int out_size, void* d_ws, size_t ws_size,
                              hipStream_t stream) {
    const float* x    = (const float*)d_in[0];
    const float* Win  = (const float*)d_in[1];
    const float* b_in = (const float*)d_in[2];
    const float* Wg   = (const float*)d_in[3];
    const float* W1   = (const float*)d_in[4];
    const float* b1   = (const float*)d_in[5];
    const float* W2   = (const float*)d_in[6];
    const float* b2   = (const float*)d_in[7];
    const float* Wh   = (const float*)d_in[8];
    float* out = (float*)d_out;

    // workspace layout (256B aligned)
    char* p = (char*)d_ws;
    size_t off = 0;
    auto alloc = [&](size_t bytes) {
        char* r = p + off;
        off = (off + bytes + 255) & ~(size_t)255;
        return r;
    };
    u16*   x_bf   = (u16*)alloc((size_t)NN * DD * 2);
    u16*   wint   = (u16*)alloc((size_t)DD * DD * 2);
    u16*   w1t    = (u16*)alloc((size_t)EE * DD * HH * 2);
    u16*   w2t    = (u16*)alloc((size_t)EE * DD * HH * 2);
    u16*   wht    = (u16*)alloc((size_t)DD * OUTD * 2);
    u16*   h_bf   = (u16*)alloc((size_t)NN * DD * 2);
    float* moe_f  = (float*)alloc((size_t)NN * DD * 4);
    u16*   moe_bf = (u16*)alloc((size_t)NN * DD * 2);
    float* Gt     = (float*)alloc((size_t)EE * DD * 4);
    float* cvec   = (float*)alloc(256);
    int*   counts = (int*)alloc(256);
    int*   offs   = (int*)alloc(256);
    int*   tok    = (int*)alloc((size_t)EE * NN * 4);
    float* wt     = (float*)alloc((size_t)EE * NN * 4);
    if (off > ws_size) return;  // workspace too small — fail loudly via wrong output

    u16* he = (u16*)d_out;  // 2N x H bf16 == exactly out_size*4 bytes; head GEMM overwrites

    hipMemsetAsync(counts, 0, 256, stream);
    hipMemsetAsync(moe_f, 0, (size_t)NN * DD * 4, stream);

    // conversions / transposes
    cvt_bf16<<<dim3(NN * DD / 4 / 256), 256, 0, stream>>>(x, x_bf, NN * DD / 4);
    transpose_cast<<<dim3(DD / 32, DD / 32, 1), 256, 0, stream>>>(Win, wint, DD, DD);
    transpose_cast<<<dim3(HH / 32, DD / 32, EE), 256, 0, stream>>>(W1, w1t, DD, HH);
    transpose_cast<<<dim3(DD / 32, HH / 32, EE), 256, 0, stream>>>(W2, w2t, HH, DD);
    transpose_cast<<<dim3(OUTD / 32, DD / 32, 1), 256, 0, stream>>>(Wh, wht, DD, OUTD);
    compute_G<<<dim3((EE * DD + EE) / 4), 256, 0, stream>>>(Win, Wg, b_in, Gt, cvec);

    // h = x@W_in + b_in  (bf16 out)
    gemm_bt<0, DD, DD><<<dim3(NN / 128, DD / 128), 256, 0, stream>>>(
        x_bf, wint, h_bf, nullptr, b_in, nullptr, nullptr, nullptr, nullptr, nullptr);

    // routing (exact fp32 logits)
    gate_kernel<<<dim3(NN / 4), 256, 0, stream>>>(x, Gt, cvec, counts, tok, wt);
    offsets_kernel<<<dim3(1), 64, 0, stream>>>(counts, offs);

    // he = relu(h_gathered @ W1[e] + b1[e])  -> bf16 slots in d_out
    gemm_bt<1, DD, HH><<<dim3(EE * 128, HH / 128), 256, 0, stream>>>(
        h_bf, w1t, he, nullptr, b1, tok, wt, counts, offs, nullptr);

    // moe += w * (he @ W2[e] + b2[e])  (atomic fp32 scatter)
    gemm_bt<2, HH, DD><<<dim3(EE * 128, DD / 128), 256, 0, stream>>>(
        he, w2t, nullptr, nullptr, b2, tok, wt, counts, offs, moe_f);

    cvt_bf16<<<dim3(NN * DD / 4 / 256), 256, 0, stream>>>(moe_f, moe_bf, NN * DD / 4);

    // out = moe @ W_head  (fp32 store)
    gemm_bt<3, DD, OUTD><<<dim3(NN / 128, OUTD / 128), 256, 0, stream>>>(
        moe_bf, wht, nullptr, out, nullptr, nullptr, nullptr, nullptr, nullptr, nullptr);
}